// Round 1
// baseline (17939.386 us; speedup 1.0000x reference)
//
#include <hip/hip_runtime.h>
#include <math.h>

#define T_ 100
#define B_ 64
#define S_ 128
#define E_ 512
#define H_ 1024
#define C_ 512
#define V_ 32000
#define TS_ 99            // T-1 steps
#define R_ (TS_ * B_)     // 6336 rows
#define NVB 500           // vocab tiles of 64

__device__ __forceinline__ float sigm_(float x) { return 1.0f / (1.0f + __expf(-x)); }
__device__ __forceinline__ float tanh_(float x) { float e = __expf(2.0f * x); return 1.0f - 2.0f / (e + 1.0f); }

__device__ __forceinline__ float wred(float v) {
    #pragma unroll
    for (int o = 32; o; o >>= 1) v += __shfl_down(v, o);
    return v;
}
__device__ __forceinline__ float wmax(float v) {
    #pragma unroll
    for (int o = 32; o; o >>= 1) v = fmaxf(v, __shfl_down(v, o));
    return v;
}

// ---------------------------------------------------------------------------
// Generic tiled GEMM-NT: C[m][n] = act(sum_k A[m][k]*Bw[n][k] + bias[n])
// M%64==0, N%64==0, K%16==0. grid = (N/64, M/64), block = 256.
// ---------------------------------------------------------------------------
template <int ACT>
__global__ __launch_bounds__(256) void gemm_nt(const float* __restrict__ A,
                                               const float* __restrict__ Bw,
                                               const float* __restrict__ bias,
                                               float* __restrict__ Cmat,
                                               int N, int K) {
    __shared__ __align__(16) float As[16][68];
    __shared__ __align__(16) float Bs[16][68];
    const int tid = threadIdx.x;
    const int m0 = blockIdx.y * 64, n0 = blockIdx.x * 64;
    const int tx = tid & 15, ty = tid >> 4;
    const int lr = tid >> 2, lk = (tid & 3) << 2;
    float acc[4][4] = {};
    const float* Ap = A + (size_t)(m0 + lr) * K + lk;
    const float* Bp = Bw + (size_t)(n0 + lr) * K + lk;
    for (int kt = 0; kt < K; kt += 16) {
        float4 av = *(const float4*)(Ap + kt);
        float4 bv = *(const float4*)(Bp + kt);
        __syncthreads();
        As[lk + 0][lr] = av.x; As[lk + 1][lr] = av.y; As[lk + 2][lr] = av.z; As[lk + 3][lr] = av.w;
        Bs[lk + 0][lr] = bv.x; Bs[lk + 1][lr] = bv.y; Bs[lk + 2][lr] = bv.z; Bs[lk + 3][lr] = bv.w;
        __syncthreads();
        #pragma unroll
        for (int kk = 0; kk < 16; ++kk) {
            float4 a = *(const float4*)&As[kk][ty << 2];
            float4 b = *(const float4*)&Bs[kk][tx << 2];
            float ar[4] = {a.x, a.y, a.z, a.w};
            float br[4] = {b.x, b.y, b.z, b.w};
            #pragma unroll
            for (int i = 0; i < 4; ++i)
                #pragma unroll
                for (int j = 0; j < 4; ++j) acc[i][j] = fmaf(ar[i], br[j], acc[i][j]);
        }
    }
    float bb[4] = {0.f, 0.f, 0.f, 0.f};
    if (bias) { float4 bv4 = *(const float4*)&bias[n0 + (tx << 2)]; bb[0]=bv4.x; bb[1]=bv4.y; bb[2]=bv4.z; bb[3]=bv4.w; }
    #pragma unroll
    for (int i = 0; i < 4; ++i) {
        float4 o;
        float v0 = acc[i][0] + bb[0], v1 = acc[i][1] + bb[1], v2 = acc[i][2] + bb[2], v3 = acc[i][3] + bb[3];
        if (ACT == 1) { v0 = tanh_(v0); v1 = tanh_(v1); v2 = tanh_(v2); v3 = tanh_(v3); }
        o.x = v0; o.y = v1; o.z = v2; o.w = v3;
        *(float4*)&Cmat[(size_t)(m0 + (ty << 2) + i) * N + n0 + (tx << 2)] = o;
    }
}

// ---------------------------------------------------------------------------
// Vocab GEMM (K=512) with fused per-row online-LSE partials over 64-col tile.
// grid = (NVB, R_/64), block = 256. pp[r*NVB + vb] = (max, sumexp)
// ---------------------------------------------------------------------------
__global__ __launch_bounds__(256) void vocab_lse(const float* __restrict__ A,
                                                 const float* __restrict__ Wv,
                                                 const float* __restrict__ bv,
                                                 float2* __restrict__ pp) {
    __shared__ __align__(16) float As[16][68];
    __shared__ __align__(16) float Bs[16][68];
    const int tid = threadIdx.x;
    const int m0 = blockIdx.y * 64, v0 = blockIdx.x * 64;
    const int tx = tid & 15, ty = tid >> 4;
    const int lr = tid >> 2, lk = (tid & 3) << 2;
    float acc[4][4] = {};
    const float* Ap = A + (size_t)(m0 + lr) * E_ + lk;
    const float* Bp = Wv + (size_t)(v0 + lr) * E_ + lk;
    for (int kt = 0; kt < E_; kt += 16) {
        float4 av = *(const float4*)(Ap + kt);
        float4 bvv = *(const float4*)(Bp + kt);
        __syncthreads();
        As[lk + 0][lr] = av.x; As[lk + 1][lr] = av.y; As[lk + 2][lr] = av.z; As[lk + 3][lr] = av.w;
        Bs[lk + 0][lr] = bvv.x; Bs[lk + 1][lr] = bvv.y; Bs[lk + 2][lr] = bvv.z; Bs[lk + 3][lr] = bvv.w;
        __syncthreads();
        #pragma unroll
        for (int kk = 0; kk < 16; ++kk) {
            float4 a = *(const float4*)&As[kk][ty << 2];
            float4 b = *(const float4*)&Bs[kk][tx << 2];
            float ar[4] = {a.x, a.y, a.z, a.w};
            float br[4] = {b.x, b.y, b.z, b.w};
            #pragma unroll
            for (int i = 0; i < 4; ++i)
                #pragma unroll
                for (int j = 0; j < 4; ++j) acc[i][j] = fmaf(ar[i], br[j], acc[i][j]);
        }
    }
    float4 bias = *(const float4*)&bv[v0 + (tx << 2)];
    float bb[4] = {bias.x, bias.y, bias.z, bias.w};
    #pragma unroll
    for (int i = 0; i < 4; ++i) {
        float x[4];
        #pragma unroll
        for (int j = 0; j < 4; ++j) x[j] = acc[i][j] + bb[j];
        float m = fmaxf(fmaxf(x[0], x[1]), fmaxf(x[2], x[3]));
        #pragma unroll
        for (int o = 8; o; o >>= 1) m = fmaxf(m, __shfl_down(m, o, 16));
        m = __shfl(m, 0, 16);
        float s = __expf(x[0] - m) + __expf(x[1] - m) + __expf(x[2] - m) + __expf(x[3] - m);
        #pragma unroll
        for (int o = 8; o; o >>= 1) s += __shfl_down(s, o, 16);
        if (tx == 0) pp[(size_t)(m0 + (ty << 2) + i) * NVB + blockIdx.x] = make_float2(m, s);
    }
}

// ---------------------------------------------------------------------------
// GRU cell step (wave-per-output GEMV). x-dim hardcoded 512 (E_==C_==512).
// grid = B_*(H_/64) = 1024, block 256.
// ---------------------------------------------------------------------------
__global__ __launch_bounds__(256) void gru_step(const float* __restrict__ xbase,
                                                const int* __restrict__ tok,
                                                const float* __restrict__ hprev,
                                                const float* __restrict__ Wih,
                                                const float* __restrict__ Whh,
                                                const float* __restrict__ bih,
                                                const float* __restrict__ bhh,
                                                float* __restrict__ hout) {
    __shared__ __align__(16) float xs[512];
    __shared__ __align__(16) float hs[1024];
    const int b = blockIdx.x >> 4, jc = blockIdx.x & 15;
    const int tid = threadIdx.x;
    const int row = tok ? tok[b] : b;
    const float* xr = xbase + (size_t)row * 512;
    for (int k = tid; k < 512; k += 256) xs[k] = xr[k];
    if (hprev) { for (int k = tid; k < 1024; k += 256) hs[k] = hprev[b * 1024 + k]; }
    else       { for (int k = tid; k < 1024; k += 256) hs[k] = 0.0f; }
    __syncthreads();
    const int wave = tid >> 6, lane = tid & 63;
    const int jbase = jc * 64;
    for (int jj = wave; jj < 64; jj += 4) {
        const int j = jbase + jj;
        float a0 = 0, a1 = 0, a2 = 0, c0 = 0, c1 = 0, c2 = 0;
        const float* w0 = Wih + (size_t)j * 512;
        const float* w1 = w0 + (size_t)H_ * 512;
        const float* w2 = w1 + (size_t)H_ * 512;
        #pragma unroll
        for (int k = lane * 4; k < 512; k += 256) {
            float4 x = *(const float4*)&xs[k];
            float4 p = *(const float4*)&w0[k]; a0 += x.x*p.x + x.y*p.y + x.z*p.z + x.w*p.w;
            float4 q = *(const float4*)&w1[k]; a1 += x.x*q.x + x.y*q.y + x.z*q.z + x.w*q.w;
            float4 r4 = *(const float4*)&w2[k]; a2 += x.x*r4.x + x.y*r4.y + x.z*r4.z + x.w*r4.w;
        }
        const float* v0 = Whh + (size_t)j * 1024;
        const float* v1 = v0 + (size_t)H_ * 1024;
        const float* v2 = v1 + (size_t)H_ * 1024;
        #pragma unroll
        for (int k = lane * 4; k < 1024; k += 256) {
            float4 h4 = *(const float4*)&hs[k];
            float4 p = *(const float4*)&v0[k]; c0 += h4.x*p.x + h4.y*p.y + h4.z*p.z + h4.w*p.w;
            float4 q = *(const float4*)&v1[k]; c1 += h4.x*q.x + h4.y*q.y + h4.z*q.z + h4.w*q.w;
            float4 r4 = *(const float4*)&v2[k]; c2 += h4.x*r4.x + h4.y*r4.y + h4.z*r4.z + h4.w*r4.w;
        }
        #pragma unroll
        for (int o = 32; o; o >>= 1) {
            a0 += __shfl_down(a0, o); a1 += __shfl_down(a1, o); a2 += __shfl_down(a2, o);
            c0 += __shfl_down(c0, o); c1 += __shfl_down(c1, o); c2 += __shfl_down(c2, o);
        }
        if (lane == 0) {
            float r = sigm_(a0 + bih[j] + c0 + bhh[j]);
            float z = sigm_(a1 + bih[H_ + j] + c1 + bhh[H_ + j]);
            float n = tanh_(a2 + bih[2 * H_ + j] + r * (c2 + bhh[2 * H_ + j]));
            hout[b * H_ + j] = (1.0f - z) * n + z * hs[j];
        }
    }
}

// hid[b][c] = sum_k h1[b][k] * W_h2c[c][k].  grid = B_*(C_/64)=512, block 256.
__global__ __launch_bounds__(256) void hid_step(const float* __restrict__ h1,
                                                const float* __restrict__ Wh2c,
                                                float* __restrict__ hid) {
    __shared__ __align__(16) float hs[1024];
    const int b = blockIdx.x >> 3, cc = blockIdx.x & 7;
    const int tid = threadIdx.x;
    for (int k = tid; k < 1024; k += 256) hs[k] = h1[b * 1024 + k];
    __syncthreads();
    const int wave = tid >> 6, lane = tid & 63;
    const int cbase = cc * 64;
    for (int ii = wave; ii < 64; ii += 4) {
        const int c = cbase + ii;
        const float* w = Wh2c + (size_t)c * 1024;
        float acc = 0;
        #pragma unroll
        for (int k = lane * 4; k < 1024; k += 256) {
            float4 h4 = *(const float4*)&hs[k];
            float4 p = *(const float4*)&w[k];
            acc += h4.x*p.x + h4.y*p.y + h4.z*p.z + h4.w*p.w;
        }
        acc = wred(acc);
        if (lane == 0) hid[b * 512 + c] = acc;
    }
}

// attention: scores -> softmax over S -> z.  grid = B_ = 64, block 256.
__global__ __launch_bounds__(256) void attn_step(const float* __restrict__ ctxp,
                                                 const float* __restrict__ ctx,
                                                 const float* __restrict__ hid,
                                                 const float* __restrict__ wmlp,
                                                 float* __restrict__ z) {
    __shared__ __align__(16) float hd[512];
    __shared__ __align__(16) float wm[512];
    __shared__ float sc[128];
    const int b = blockIdx.x;
    const int tid = threadIdx.x;
    for (int k = tid; k < 512; k += 256) { hd[k] = hid[b * 512 + k]; wm[k] = wmlp[k]; }
    __syncthreads();
    const int wave = tid >> 6, lane = tid & 63;
    for (int s = wave; s < 128; s += 4) {
        const float* cp = ctxp + ((size_t)s * B_ + b) * 512;
        float acc = 0;
        #pragma unroll
        for (int c = lane * 4; c < 512; c += 256) {
            float4 v = *(const float4*)&cp[c];
            float4 h4 = *(const float4*)&hd[c];
            float4 w4 = *(const float4*)&wm[c];
            acc += tanh_(v.x + h4.x) * w4.x + tanh_(v.y + h4.y) * w4.y +
                   tanh_(v.z + h4.z) * w4.z + tanh_(v.w + h4.w) * w4.w;
        }
        acc = wred(acc);
        if (lane == 0) sc[s] = acc;
    }
    __syncthreads();
    if (wave == 0) {
        float s0 = sc[lane], s1 = sc[lane + 64];
        float m = fmaxf(s0, s1);
        m = wmax(m); m = __shfl(m, 0);
        float e0 = __expf(s0 - m), e1 = __expf(s1 - m);
        float ssum = wred(e0 + e1); ssum = __shfl(ssum, 0);
        float inv = 1.0f / ssum;
        sc[lane] = e0 * inv; sc[lane + 64] = e1 * inv;
    }
    __syncthreads();
    for (int c = tid; c < 512; c += 256) {
        float acc = 0;
        #pragma unroll 8
        for (int s = 0; s < 128; ++s) acc += sc[s] * ctx[((size_t)s * B_ + b) * 512 + c];
        z[b * 512 + c] = acc;
    }
}

// combine LSE partials + target logit -> per-row loss. grid = R_, block 64.
__global__ __launch_bounds__(64) void row_loss_k(const float2* __restrict__ pp,
                                                 const float* __restrict__ logit_all,
                                                 const float* __restrict__ Wv,
                                                 const float* __restrict__ bv,
                                                 const int* __restrict__ y,
                                                 float* __restrict__ rl) {
    const int r = blockIdx.x;
    const int lane = threadIdx.x;
    const int t = r / B_, b = r % B_;
    const int tgt = y[(t + 1) * B_ + b];
    float m = -1e30f;
    for (int i = lane; i < NVB; i += 64) m = fmaxf(m, pp[(size_t)r * NVB + i].x);
    m = wmax(m); m = __shfl(m, 0);
    float s = 0;
    for (int i = lane; i < NVB; i += 64) {
        float2 p = pp[(size_t)r * NVB + i];
        s += p.y * __expf(p.x - m);
    }
    s = wred(s);
    float d = 0;
    for (int k = lane; k < E_; k += 64) d += logit_all[(size_t)r * E_ + k] * Wv[(size_t)tgt * E_ + k];
    d = wred(d);
    if (lane == 0) {
        float lse = m + logf(s);
        rl[r] = (tgt != 0) ? (lse - (d + bv[tgt])) : 0.0f;
    }
}

__global__ __launch_bounds__(256) void sum_k(const float* __restrict__ rl, float* __restrict__ out) {
    float s = 0;
    for (int i = threadIdx.x; i < R_; i += 256) s += rl[i];
    __shared__ float red[4];
    s = wred(s);
    if ((threadIdx.x & 63) == 0) red[threadIdx.x >> 6] = s;
    __syncthreads();
    if (threadIdx.x == 0) out[0] = red[0] + red[1] + red[2] + red[3];
}

extern "C" void kernel_launch(void* const* d_in, const int* in_sizes, int n_in,
                              void* d_out, int out_size, void* d_ws, size_t ws_size,
                              hipStream_t stream) {
    const int*   y     = (const int*)d_in[0];
    const float* ctx   = (const float*)d_in[1];
    const float* emb   = (const float*)d_in[2];
    const float* W_ih0 = (const float*)d_in[3];
    const float* W_hh0 = (const float*)d_in[4];
    const float* b_ih0 = (const float*)d_in[5];
    const float* b_hh0 = (const float*)d_in[6];
    const float* W_ih1 = (const float*)d_in[7];
    const float* W_hh1 = (const float*)d_in[8];
    const float* b_ih1 = (const float*)d_in[9];
    const float* b_hh1 = (const float*)d_in[10];
    const float* W_c2c = (const float*)d_in[11];
    const float* W_h2c = (const float*)d_in[12];
    const float* w_mlp = (const float*)d_in[13];
    const float* W_h2o = (const float*)d_in[14];
    const float* b_h2o = (const float*)d_in[15];
    const float* W_o2p = (const float*)d_in[16];
    const float* b_o2p = (const float*)d_in[17];
    float* out = (float*)d_out;

    float* ws = (float*)d_ws;
    float* ctx_p     = ws;                 ws += (size_t)S_ * B_ * C_;   // 4,194,304
    float* h1        = ws;                 ws += (size_t)B_ * H_;        // 65,536
    float* hid       = ws;                 ws += (size_t)B_ * C_;        // 32,768
    float* z         = ws;                 ws += (size_t)B_ * C_;        // 32,768
    float* h2_all    = ws;                 ws += (size_t)R_ * H_;        // 6,488,064
    float* logit_all = ws;                 ws += (size_t)R_ * E_;        // 3,244,032
    float2* pp       = (float2*)ws;        ws += (size_t)R_ * NVB * 2;   // 6,336,000
    float* rl        = ws;                 ws += R_;

    // ctx_p = einsum('sbc,kc->sbk', ctx, W_c2c)
    gemm_nt<0><<<dim3(C_ / 64, (S_ * B_) / 64), 256, 0, stream>>>(ctx, W_c2c, nullptr, ctx_p, C_, C_);

    for (int t = 0; t < TS_; ++t) {
        const float* hp = t ? (h2_all + (size_t)(t - 1) * B_ * H_) : nullptr;
        gru_step<<<B_ * (H_ / 64), 256, 0, stream>>>(emb, y + t * B_, hp,
                                                     W_ih0, W_hh0, b_ih0, b_hh0, h1);
        hid_step<<<B_ * (C_ / 64), 256, 0, stream>>>(h1, W_h2c, hid);
        attn_step<<<B_, 256, 0, stream>>>(ctx_p, ctx, hid, w_mlp, z);
        gru_step<<<B_ * (H_ / 64), 256, 0, stream>>>(z, nullptr, h1,
                                                     W_ih1, W_hh1, b_ih1, b_hh1,
                                                     h2_all + (size_t)t * B_ * H_);
    }

    // logit = tanh(h2 @ W_h2o^T + b_h2o), batched over all steps
    gemm_nt<1><<<dim3(E_ / 64, R_ / 64), 256, 0, stream>>>(h2_all, W_h2o, b_h2o, logit_all, E_, H_);
    // vocab GEMM + fused LSE partials
    vocab_lse<<<dim3(NVB, R_ / 64), 256, 0, stream>>>(logit_all, W_o2p, b_o2p, pp);
    // per-row loss, then total
    row_loss_k<<<R_, 64, 0, stream>>>(pp, logit_all, W_o2p, b_o2p, y, rl);
    sum_k<<<1, 256, 0, stream>>>(rl, out);
}

// Round 2
// 8820.735 us; speedup vs baseline: 2.0338x; 2.0338x over previous
//
#include <hip/hip_runtime.h>
#include <math.h>

#define T_ 100
#define B_ 64
#define S_ 128
#define E_ 512
#define H_ 1024
#define C_ 512
#define V_ 32000
#define TS_ 99            // T-1 steps
#define R_ (TS_ * B_)     // 6336 rows
#define MP_ 6400          // rows padded to multiple of 128 for MFMA
#define NT2 250           // vocab n-tiles of 128

typedef unsigned short ushort_t;
typedef __attribute__((ext_vector_type(8))) short short8;
typedef __attribute__((ext_vector_type(4))) float f32x4;

__device__ __forceinline__ float sigm_(float x) { return 1.0f / (1.0f + __expf(-x)); }
__device__ __forceinline__ float tanh_(float x) { float e = __expf(2.0f * x); return 1.0f - 2.0f / (e + 1.0f); }
__device__ __forceinline__ ushort_t f2bf(float f) {
    unsigned u = __float_as_uint(f);
    unsigned r = (u + 0x7FFF + ((u >> 16) & 1)) >> 16;
    return (ushort_t)r;
}

__device__ __forceinline__ float wred(float v) {
    #pragma unroll
    for (int o = 32; o; o >>= 1) v += __shfl_down(v, o);
    return v;
}
__device__ __forceinline__ float wmax(float v) {
    #pragma unroll
    for (int o = 32; o; o >>= 1) v = fmaxf(v, __shfl_down(v, o));
    return v;
}

// ---------------------------------------------------------------------------
// fp32 tiled GEMM-NT (used only for ctx_p precompute): C[m][n] = sum_k A[m][k]*Bw[n][k]
// ---------------------------------------------------------------------------
__global__ __launch_bounds__(256) void gemm_nt(const float* __restrict__ A,
                                               const float* __restrict__ Bw,
                                               float* __restrict__ Cmat,
                                               int N, int K) {
    __shared__ __align__(16) float As[16][68];
    __shared__ __align__(16) float Bs[16][68];
    const int tid = threadIdx.x;
    const int m0 = blockIdx.y * 64, n0 = blockIdx.x * 64;
    const int tx = tid & 15, ty = tid >> 4;
    const int lr = tid >> 2, lk = (tid & 3) << 2;
    float acc[4][4] = {};
    const float* Ap = A + (size_t)(m0 + lr) * K + lk;
    const float* Bp = Bw + (size_t)(n0 + lr) * K + lk;
    for (int kt = 0; kt < K; kt += 16) {
        float4 av = *(const float4*)(Ap + kt);
        float4 bv = *(const float4*)(Bp + kt);
        __syncthreads();
        As[lk + 0][lr] = av.x; As[lk + 1][lr] = av.y; As[lk + 2][lr] = av.z; As[lk + 3][lr] = av.w;
        Bs[lk + 0][lr] = bv.x; Bs[lk + 1][lr] = bv.y; Bs[lk + 2][lr] = bv.z; Bs[lk + 3][lr] = bv.w;
        __syncthreads();
        #pragma unroll
        for (int kk = 0; kk < 16; ++kk) {
            float4 a = *(const float4*)&As[kk][ty << 2];
            float4 b = *(const float4*)&Bs[kk][tx << 2];
            float ar[4] = {a.x, a.y, a.z, a.w};
            float br[4] = {b.x, b.y, b.z, b.w};
            #pragma unroll
            for (int i = 0; i < 4; ++i)
                #pragma unroll
                for (int j = 0; j < 4; ++j) acc[i][j] = fmaf(ar[i], br[j], acc[i][j]);
        }
    }
    #pragma unroll
    for (int i = 0; i < 4; ++i) {
        float4 o = {acc[i][0], acc[i][1], acc[i][2], acc[i][3]};
        *(float4*)&Cmat[(size_t)(m0 + (ty << 2) + i) * N + n0 + (tx << 2)] = o;
    }
}

// ---------------------------------------------------------------------------
// Per-step GRU partial GEMM: P[ks][64][3072], K split into 12 slices of 128.
// ks 0..3 -> x-source (K=512), ks 4..11 -> h-source (K=1024).
// grid (48, 12), block 256. Weights read exactly once per step.
// ---------------------------------------------------------------------------
__global__ __launch_bounds__(256) void gru_partial(const float* __restrict__ Ax, int ldax,
                                                   const float* __restrict__ Wx,
                                                   const float* __restrict__ Ah, int ldah,
                                                   const float* __restrict__ Wh,
                                                   float* __restrict__ P) {
    const int n0 = blockIdx.x * 64, ks = blockIdx.y;
    const int tid = threadIdx.x;
    const int tx = tid & 15, ty = tid >> 4;
    const int lr = tid >> 2, lk = (tid & 3) << 2;
    const float* Ap;
    const float* Wp;
    if (ks < 4) {
        Ap = Ax + (size_t)lr * ldax + ks * 128 + lk;
        Wp = Wx + (size_t)(n0 + lr) * 512 + ks * 128 + lk;
    } else {
        if (!Ah) {  // t==0: h_prev = 0 -> zero partials
            float4 zz = {0.f, 0.f, 0.f, 0.f};
            #pragma unroll
            for (int i = 0; i < 4; ++i)
                *(float4*)&P[((size_t)ks * 64 + (ty << 2) + i) * 3072 + n0 + (tx << 2)] = zz;
            return;
        }
        int kb = (ks - 4) * 128;
        Ap = Ah + (size_t)lr * ldah + kb + lk;
        Wp = Wh + (size_t)(n0 + lr) * 1024 + kb + lk;
    }
    __shared__ __align__(16) float As[16][68];
    __shared__ __align__(16) float Bs[16][68];
    float acc[4][4] = {};
    for (int kt = 0; kt < 128; kt += 16) {
        float4 av = *(const float4*)(Ap + kt);
        float4 bv = *(const float4*)(Wp + kt);
        __syncthreads();
        As[lk + 0][lr] = av.x; As[lk + 1][lr] = av.y; As[lk + 2][lr] = av.z; As[lk + 3][lr] = av.w;
        Bs[lk + 0][lr] = bv.x; Bs[lk + 1][lr] = bv.y; Bs[lk + 2][lr] = bv.z; Bs[lk + 3][lr] = bv.w;
        __syncthreads();
        #pragma unroll
        for (int kk = 0; kk < 16; ++kk) {
            float4 a = *(const float4*)&As[kk][ty << 2];
            float4 b = *(const float4*)&Bs[kk][tx << 2];
            float ar[4] = {a.x, a.y, a.z, a.w};
            float br[4] = {b.x, b.y, b.z, b.w};
            #pragma unroll
            for (int i = 0; i < 4; ++i)
                #pragma unroll
                for (int j = 0; j < 4; ++j) acc[i][j] = fmaf(ar[i], br[j], acc[i][j]);
        }
    }
    #pragma unroll
    for (int i = 0; i < 4; ++i) {
        float4 o = {acc[i][0], acc[i][1], acc[i][2], acc[i][3]};
        *(float4*)&P[((size_t)ks * 64 + (ty << 2) + i) * 3072 + n0 + (tx << 2)] = o;
    }
}

// Generic single-source partial GEMM (used for hid): P[ks][64][N], K slice 128.
__global__ __launch_bounds__(256) void partial_gemm(const float* __restrict__ A, int lda,
                                                    const float* __restrict__ W, int ldw,
                                                    float* __restrict__ P, int N) {
    const int n0 = blockIdx.x * 64, ks = blockIdx.y;
    const int tid = threadIdx.x;
    const int tx = tid & 15, ty = tid >> 4;
    const int lr = tid >> 2, lk = (tid & 3) << 2;
    const float* Ap = A + (size_t)lr * lda + ks * 128 + lk;
    const float* Wp = W + (size_t)(n0 + lr) * ldw + ks * 128 + lk;
    __shared__ __align__(16) float As[16][68];
    __shared__ __align__(16) float Bs[16][68];
    float acc[4][4] = {};
    for (int kt = 0; kt < 128; kt += 16) {
        float4 av = *(const float4*)(Ap + kt);
        float4 bv = *(const float4*)(Wp + kt);
        __syncthreads();
        As[lk + 0][lr] = av.x; As[lk + 1][lr] = av.y; As[lk + 2][lr] = av.z; As[lk + 3][lr] = av.w;
        Bs[lk + 0][lr] = bv.x; Bs[lk + 1][lr] = bv.y; Bs[lk + 2][lr] = bv.z; Bs[lk + 3][lr] = bv.w;
        __syncthreads();
        #pragma unroll
        for (int kk = 0; kk < 16; ++kk) {
            float4 a = *(const float4*)&As[kk][ty << 2];
            float4 b = *(const float4*)&Bs[kk][tx << 2];
            float ar[4] = {a.x, a.y, a.z, a.w};
            float br[4] = {b.x, b.y, b.z, b.w};
            #pragma unroll
            for (int i = 0; i < 4; ++i)
                #pragma unroll
                for (int j = 0; j < 4; ++j) acc[i][j] = fmaf(ar[i], br[j], acc[i][j]);
        }
    }
    #pragma unroll
    for (int i = 0; i < 4; ++i) {
        float4 o = {acc[i][0], acc[i][1], acc[i][2], acc[i][3]};
        *(float4*)&P[((size_t)ks * 64 + (ty << 2) + i) * N + n0 + (tx << 2)] = o;
    }
}

// GRU gate combine: sums 12 partial slices + biases -> gates -> h_out.
// grid 256 blocks x 256 threads, one thread per (b, j).
__global__ __launch_bounds__(256) void gru_gate(const float* __restrict__ P,
                                                const float* __restrict__ bi,
                                                const float* __restrict__ bh,
                                                const float* __restrict__ hp, int ldhp,
                                                float* __restrict__ hout, int ldout) {
    const int idx = blockIdx.x * 256 + threadIdx.x;
    const int b = idx >> 10, j = idx & 1023;
    float ir = bi[j], iz = bi[1024 + j], in_ = bi[2048 + j];
    float hr = bh[j], hz = bh[1024 + j], hn = bh[2048 + j];
    #pragma unroll
    for (int ks = 0; ks < 4; ++ks) {
        const float* q = P + ((size_t)ks * 64 + b) * 3072;
        ir += q[j]; iz += q[1024 + j]; in_ += q[2048 + j];
    }
    #pragma unroll
    for (int ks = 4; ks < 12; ++ks) {
        const float* q = P + ((size_t)ks * 64 + b) * 3072;
        hr += q[j]; hz += q[1024 + j]; hn += q[2048 + j];
    }
    float hprev = hp ? hp[(size_t)b * ldhp + j] : 0.0f;
    float r = sigm_(ir + hr);
    float z = sigm_(iz + hz);
    float n = tanh_(in_ + r * hn);
    hout[(size_t)b * ldout + j] = (1.0f - z) * n + z * hprev;
}

// attention: sums hid partials (8 slices), scores -> softmax over S -> z.
// grid = B_ = 64, block 256. Writes z into zh1[b][0..511].
__global__ __launch_bounds__(256) void attn_step(const float* __restrict__ ctxp,
                                                 const float* __restrict__ ctx,
                                                 const float* __restrict__ Ph,
                                                 const float* __restrict__ wmlp,
                                                 float* __restrict__ zh1) {
    __shared__ __align__(16) float hd[512];
    __shared__ __align__(16) float wm[512];
    __shared__ float sc[128];
    const int b = blockIdx.x;
    const int tid = threadIdx.x;
    for (int k = tid; k < 512; k += 256) {
        float s = 0;
        #pragma unroll
        for (int p = 0; p < 8; ++p) s += Ph[((size_t)p * 64 + b) * 512 + k];
        hd[k] = s;
        wm[k] = wmlp[k];
    }
    __syncthreads();
    const int wave = tid >> 6, lane = tid & 63;
    for (int s = wave; s < 128; s += 4) {
        const float* cp = ctxp + ((size_t)s * B_ + b) * 512;
        float acc = 0;
        #pragma unroll
        for (int c = lane * 4; c < 512; c += 256) {
            float4 v = *(const float4*)&cp[c];
            float4 h4 = *(const float4*)&hd[c];
            float4 w4 = *(const float4*)&wm[c];
            acc += tanh_(v.x + h4.x) * w4.x + tanh_(v.y + h4.y) * w4.y +
                   tanh_(v.z + h4.z) * w4.z + tanh_(v.w + h4.w) * w4.w;
        }
        acc = wred(acc);
        if (lane == 0) sc[s] = acc;
    }
    __syncthreads();
    if (wave == 0) {
        float s0 = sc[lane], s1 = sc[lane + 64];
        float m = fmaxf(s0, s1);
        m = wmax(m); m = __shfl(m, 0);
        float e0 = __expf(s0 - m), e1 = __expf(s1 - m);
        float ssum = wred(e0 + e1); ssum = __shfl(ssum, 0);
        float inv = 1.0f / ssum;
        sc[lane] = e0 * inv; sc[lane + 64] = e1 * inv;
    }
    __syncthreads();
    for (int c = tid; c < 512; c += 256) {
        float acc = 0;
        #pragma unroll 8
        for (int s = 0; s < 128; ++s) acc += sc[s] * ctx[((size_t)s * B_ + b) * 512 + c];
        zh1[(size_t)b * 1536 + c] = acc;
    }
}

// ---------------------------------------------------------------------------
// bf16 MFMA GEMM-NT, 128x128 tile, K-chunk 64 via LDS (padded stride 72).
// EPI==1: tanh(acc+bias) -> fp32 C and bf16 C2.  EPI==2: fused per-row
// online-LSE partials over the 128-col tile -> pp[row][ntile]=(max,sum).
// grid (N/128, M/128), block 256 (4 waves, each 64x64 via 4x4 of 16x16x32).
// ---------------------------------------------------------------------------
template <int EPI>
__global__ __launch_bounds__(256) void mfma_nt(const ushort_t* __restrict__ A,
                                               const ushort_t* __restrict__ Bw,
                                               const float* __restrict__ bias,
                                               float* __restrict__ Cf,
                                               ushort_t* __restrict__ Cbf,
                                               float2* __restrict__ pp,
                                               int N, int K, int NT) {
    __shared__ ushort_t As[128 * 72];
    __shared__ ushort_t Bs[128 * 72];
    __shared__ float smM[2][128], smS[2][128];
    const int tid = threadIdx.x;
    const int m0 = blockIdx.y * 128, n0 = blockIdx.x * 128;
    const int w = tid >> 6, lane = tid & 63;
    const int quad = lane >> 4, l16 = lane & 15;
    f32x4 acc[4][4] = {};
    for (int kc = 0; kc < K; kc += 64) {
        __syncthreads();
        #pragma unroll
        for (int i = 0; i < 4; ++i) {
            int cid = i * 256 + tid;
            int row = cid >> 3, c8 = cid & 7;
            uint4 va = *(const uint4*)(A + (size_t)(m0 + row) * K + kc + c8 * 8);
            *(uint4*)(&As[row * 72 + c8 * 8]) = va;
            uint4 vb = *(const uint4*)(Bw + (size_t)(n0 + row) * K + kc + c8 * 8);
            *(uint4*)(&Bs[row * 72 + c8 * 8]) = vb;
        }
        __syncthreads();
        #pragma unroll
        for (int ks = 0; ks < 2; ++ks) {
            short8 af[4], bfr[4];
            #pragma unroll
            for (int i = 0; i < 4; ++i)
                af[i] = *(const short8*)(&As[((w >> 1) * 64 + i * 16 + l16) * 72 + ks * 32 + quad * 8]);
            #pragma unroll
            for (int j = 0; j < 4; ++j)
                bfr[j] = *(const short8*)(&Bs[((w & 1) * 64 + j * 16 + l16) * 72 + ks * 32 + quad * 8]);
            #pragma unroll
            for (int i = 0; i < 4; ++i)
                #pragma unroll
                for (int j = 0; j < 4; ++j)
                    acc[i][j] = __builtin_amdgcn_mfma_f32_16x16x32_bf16(af[i], bfr[j], acc[i][j], 0, 0, 0);
        }
    }
    const int colbase = n0 + (w & 1) * 64;
    const int rowbase = m0 + (w >> 1) * 64;
    if (EPI == 1) {
        #pragma unroll
        for (int j = 0; j < 4; ++j) {
            int col = colbase + j * 16 + l16;
            float bv = bias[col];
            #pragma unroll
            for (int i = 0; i < 4; ++i) {
                #pragma unroll
                for (int r = 0; r < 4; ++r) {
                    int row = rowbase + i * 16 + quad * 4 + r;
                    float v = tanh_(acc[i][j][r] + bv);
                    Cf[(size_t)row * N + col] = v;
                    Cbf[(size_t)row * N + col] = f2bf(v);
                }
            }
        }
    } else {  // EPI == 2: LSE partials
        float bv[4];
        #pragma unroll
        for (int j = 0; j < 4; ++j) bv[j] = bias[colbase + j * 16 + l16];
        #pragma unroll
        for (int i = 0; i < 4; ++i) {
            #pragma unroll
            for (int r = 0; r < 4; ++r) {
                float x0 = acc[i][0][r] + bv[0], x1 = acc[i][1][r] + bv[1];
                float x2 = acc[i][2][r] + bv[2], x3 = acc[i][3][r] + bv[3];
                float mx = fmaxf(fmaxf(x0, x1), fmaxf(x2, x3));
                #pragma unroll
                for (int o = 1; o < 16; o <<= 1) mx = fmaxf(mx, __shfl_xor(mx, o));
                float s = __expf(x0 - mx) + __expf(x1 - mx) + __expf(x2 - mx) + __expf(x3 - mx);
                #pragma unroll
                for (int o = 1; o < 16; o <<= 1) s += __shfl_xor(s, o);
                if (l16 == 0) {
                    int rr = (w >> 1) * 64 + i * 16 + quad * 4 + r;
                    smM[w & 1][rr] = mx;
                    smS[w & 1][rr] = s;
                }
            }
        }
        __syncthreads();
        if (tid < 128) {
            float ma = smM[0][tid], mb = smM[1][tid];
            float M = fmaxf(ma, mb);
            float S = smS[0][tid] * __expf(ma - M) + smS[1][tid] * __expf(mb - M);
            pp[(size_t)(m0 + tid) * NT + blockIdx.x] = make_float2(M, S);
        }
    }
}

// fp32 -> bf16 convert with zero-pad beyond n_valid. block 256, 4 elems/thread.
__global__ __launch_bounds__(256) void conv_bf16(const float* __restrict__ src,
                                                 ushort_t* __restrict__ dst,
                                                 long long n_valid, long long n_total) {
    long long base = ((long long)blockIdx.x * 256 + threadIdx.x) * 4;
    if (base >= n_total) return;
    ushort_t o[4] = {0, 0, 0, 0};
    if (base < n_valid) {
        float4 v = *(const float4*)(src + base);
        o[0] = f2bf(v.x); o[1] = f2bf(v.y); o[2] = f2bf(v.z); o[3] = f2bf(v.w);
    }
    *(ushort2*)(dst + base) = make_ushort2(o[0], o[1]);
    *(ushort2*)(dst + base + 2) = make_ushort2(o[2], o[3]);
}

// gather embedding rows for all (t,b): x_emb_all[r] = emb[y[r]], fp32.
__global__ __launch_bounds__(128) void gather_emb(const float* __restrict__ emb,
                                                  const int* __restrict__ y,
                                                  float* __restrict__ xall) {
    const int r = blockIdx.x;
    const int tok = y[r];
    const float* src = emb + (size_t)tok * 512;
    float* dst = xall + (size_t)r * 512;
    int k = threadIdx.x * 4;
    *(float4*)(dst + k) = *(const float4*)(src + k);
}

// combine LSE partials + target logit -> per-row loss. grid = R_, block 64.
__global__ __launch_bounds__(64) void row_loss_k(const float2* __restrict__ pp,
                                                 const float* __restrict__ logit_all,
                                                 const float* __restrict__ Wv,
                                                 const float* __restrict__ bv,
                                                 const int* __restrict__ y,
                                                 float* __restrict__ rl) {
    const int r = blockIdx.x;
    const int lane = threadIdx.x;
    const int t = r / B_, b = r % B_;
    const int tgt = y[(t + 1) * B_ + b];
    float m = -1e30f;
    for (int i = lane; i < NT2; i += 64) m = fmaxf(m, pp[(size_t)r * NT2 + i].x);
    m = wmax(m); m = __shfl(m, 0);
    float s = 0;
    for (int i = lane; i < NT2; i += 64) {
        float2 p = pp[(size_t)r * NT2 + i];
        s += p.y * __expf(p.x - m);
    }
    s = wred(s);
    float d = 0;
    for (int k = lane; k < E_; k += 64) d += logit_all[(size_t)r * E_ + k] * Wv[(size_t)tgt * E_ + k];
    d = wred(d);
    if (lane == 0) {
        float lse = m + logf(s);
        rl[r] = (tgt != 0) ? (lse - (d + bv[tgt])) : 0.0f;
    }
}

__global__ __launch_bounds__(256) void sum_k(const float* __restrict__ rl, float* __restrict__ out) {
    float s = 0;
    for (int i = threadIdx.x; i < R_; i += 256) s += rl[i];
    __shared__ float red[4];
    s = wred(s);
    if ((threadIdx.x & 63) == 0) red[threadIdx.x >> 6] = s;
    __syncthreads();
    if (threadIdx.x == 0) out[0] = red[0] + red[1] + red[2] + red[3];
}

extern "C" void kernel_launch(void* const* d_in, const int* in_sizes, int n_in,
                              void* d_out, int out_size, void* d_ws, size_t ws_size,
                              hipStream_t stream) {
    const int*   y     = (const int*)d_in[0];
    const float* ctx   = (const float*)d_in[1];
    const float* emb   = (const float*)d_in[2];
    const float* W_ih0 = (const float*)d_in[3];
    const float* W_hh0 = (const float*)d_in[4];
    const float* b_ih0 = (const float*)d_in[5];
    const float* b_hh0 = (const float*)d_in[6];
    const float* W_ih1 = (const float*)d_in[7];
    const float* W_hh1 = (const float*)d_in[8];
    const float* b_ih1 = (const float*)d_in[9];
    const float* b_hh1 = (const float*)d_in[10];
    const float* W_c2c = (const float*)d_in[11];
    const float* W_h2c = (const float*)d_in[12];
    const float* w_mlp = (const float*)d_in[13];
    const float* W_h2o = (const float*)d_in[14];
    const float* b_h2o = (const float*)d_in[15];
    const float* W_o2p = (const float*)d_in[16];
    const float* b_o2p = (const float*)d_in[17];
    float* out = (float*)d_out;

    float* ws = (float*)d_ws;
    float* ctx_p    = ws; ws += (size_t)S_ * B_ * C_;        // 4,194,304
    float* x_emb    = ws; ws += (size_t)R_ * E_;             // 3,244,032
    float* P        = ws; ws += (size_t)12 * 64 * 3072;      // 2,359,296
    float* Ph       = ws; ws += (size_t)8 * 64 * 512;        // 262,144
    float* zh1      = ws; ws += (size_t)64 * 1536;           // 98,304
    float* h2_all   = ws; ws += (size_t)R_ * H_;             // 6,488,064
    ushort_t* h2_bf = (ushort_t*)ws; ws += (size_t)MP_ * H_ / 2;       // 3,276,800
    float* logit_all= ws; ws += (size_t)MP_ * E_;            // 3,276,800
    ushort_t* lg_bf = (ushort_t*)ws; ws += (size_t)MP_ * E_ / 2;       // 1,638,400
    ushort_t* Wh2o_bf = (ushort_t*)ws; ws += (size_t)E_ * H_ / 2;      // 262,144
    ushort_t* Wo2p_bf = (ushort_t*)ws; ws += (size_t)V_ * E_ / 2;      // 8,192,000
    float2* pp      = (float2*)ws; ws += (size_t)MP_ * NT2 * 2;        // 3,200,000
    float* rl       = ws; ws += R_;

    // ---- batched precompute ----
    gemm_nt<<<dim3(C_ / 64, (S_ * B_) / 64), 256, 0, stream>>>(ctx, W_c2c, ctx_p, C_, C_);
    gather_emb<<<R_, 128, 0, stream>>>(emb, y, x_emb);
    conv_bf16<<<((size_t)E_ * H_ / 4 + 255) / 256, 256, 0, stream>>>(W_h2o, Wh2o_bf, (long long)E_ * H_, (long long)E_ * H_);
    conv_bf16<<<((size_t)V_ * E_ / 4 + 255) / 256, 256, 0, stream>>>(W_o2p, Wo2p_bf, (long long)V_ * E_, (long long)V_ * E_);

    // ---- sequential decode loop ----
    for (int t = 0; t < TS_; ++t) {
        const float* hp = t ? (h2_all + (size_t)(t - 1) * B_ * H_) : nullptr;
        // GRU0: x-part from gathered emb rows, h-part from h_prev
        gru_partial<<<dim3(48, 12), 256, 0, stream>>>(x_emb + (size_t)t * B_ * E_, E_, W_ih0,
                                                      hp, H_, W_hh0, P);
        gru_gate<<<256, 256, 0, stream>>>(P, b_ih0, b_hh0, hp, H_, zh1 + 512, 1536);
        // hid = h1 @ W_h2c^T
        partial_gemm<<<dim3(8, 8), 256, 0, stream>>>(zh1 + 512, 1536, W_h2c, H_, Ph, C_);
        // attention -> z (into zh1 cols 0..511)
        attn_step<<<B_, 256, 0, stream>>>(ctx_p, ctx, Ph, w_mlp, zh1);
        // GRU1: x-part = z, h-part = h1 (both in zh1)
        gru_partial<<<dim3(48, 12), 256, 0, stream>>>(zh1, 1536, W_ih1,
                                                      zh1 + 512, 1536, W_hh1, P);
        gru_gate<<<256, 256, 0, stream>>>(P, b_ih1, b_hh1, zh1 + 512, 1536,
                                          h2_all + (size_t)t * B_ * H_, H_);
    }

    // ---- batched tail (bf16 MFMA) ----
    conv_bf16<<<((size_t)MP_ * H_ / 4 + 255) / 256, 256, 0, stream>>>(h2_all, h2_bf, (long long)R_ * H_, (long long)MP_ * H_);
    // logit = tanh(h2 @ W_h2o^T + b) -> fp32 + bf16
    mfma_nt<1><<<dim3(E_ / 128, MP_ / 128), 256, 0, stream>>>(h2_bf, Wh2o_bf, b_h2o,
                                                              logit_all, lg_bf, nullptr, E_, H_, 0);
    // vocab GEMM + fused LSE partials
    mfma_nt<2><<<dim3(V_ / 128, MP_ / 128), 256, 0, stream>>>(lg_bf, Wo2p_bf, b_o2p,
                                                              nullptr, nullptr, pp, V_, E_, NT2);
    row_loss_k<<<R_, 64, 0, stream>>>(pp, logit_all, W_o2p, b_o2p, y, rl);
    sum_k<<<1, 256, 0, stream>>>(rl, out);
}